// Round 14
// baseline (23.424 us; speedup 1.0000x reference)
//
#include <hip/hip_runtime.h>
#include <math.h>

// Tropical (min-plus) matmul: out[b, j] = min_i (X[b, i] + W[j, i])
// X: [1024][512] fp32, W: [512][512] fp32, out: [1024][512] fp32.
//
// Round 14: fp16 main (r13) restructured for 2 blocks/CU = 32 waves/CU.
// r13 lesson: halving all pipe bytes (fp16) changed nothing -> main is
// issue/latency-bound at 16 lockstep waves/CU, not pipe-bound. Fix = TLP:
//  - b-tile 4, j-tile 256: grid (2 x 256) = 512 blocks = 2/CU.
//  - LDS: Xs 4 KB + part[16][4][64] uint4 (packed fp16 pairs) 64 KB = 68 KB
//    -> two blocks co-resident; their phases interleave and fill stall gaps.
//  - VGPR <= 64 via __launch_bounds__(1024, 2) (r5: 2nd arg empirically acts
//    as blocks/CU -> 2048/32 = 64 cap) + lean live set: acc2 16 + one
//    quarter's W 16 + temps (#pragma unroll 1 on qt loop stops W hoisting).
//  - Wave k-chunk 32 = 4 k8-quarters; W loaded per qt (no ping-pong; 32-wave
//    TLP hides L2 latency). Combine reads packed pairs, pk_min, final
//    halve-min -> f32 coalesced stores.
// Spill tripwire: if WRITE_SIZE >> 2.3 MB the 64-cap forced scratch -> revert.

#define B_DIM   1024
#define IN_DIM  512
#define OUT_DIM 512

typedef unsigned int uint;

__device__ __forceinline__ uint pk2(float a, float b) {
    unsigned short ua = __builtin_bit_cast(unsigned short, (_Float16)a);
    unsigned short ub = __builtin_bit_cast(unsigned short, (_Float16)b);
    return (uint)ua | ((uint)ub << 16);
}

__device__ __forceinline__ float h_lo(uint u) {
    return (float)__builtin_bit_cast(_Float16, (unsigned short)(u & 0xffff));
}
__device__ __forceinline__ float h_hi(uint u) {
    return (float)__builtin_bit_cast(_Float16, (unsigned short)(u >> 16));
}

__device__ __forceinline__ uint pk_add_h(uint a, uint b) {
    uint d;
    asm("v_pk_add_f16 %0, %1, %2" : "=v"(d) : "v"(a), "v"(b));
    return d;
}
__device__ __forceinline__ uint pk_min_h(uint a, uint b) {
    uint d;
    asm("v_pk_min_f16 %0, %1, %2" : "=v"(d) : "v"(a), "v"(b));
    return d;
}

// ---------------- prepass: pack X -> fp16, W -> WT8[k8][j] (transposed) ----
__global__ __launch_bounds__(256)
void MinPlus_pack_h(const float* __restrict__ X, const float* __restrict__ W,
                    uint* __restrict__ Xh, uint4* __restrict__ WT8) {
    const int tid = threadIdx.x;
    const int bid = blockIdx.x;

    if (bid < 64) {
        // ---- W tile (64 j x 64 k): load coalesced, transpose via LDS ----
        __shared__ float Ls[64][68];
        const int j0 = (bid & 7) * 64;
        const int k0 = (bid >> 3) * 64;
#pragma unroll
        for (int r = 0; r < 4; ++r) {
            const int jj = (tid >> 4) + r * 16;
            const int kq = tid & 15;
            const float4 v = *reinterpret_cast<const float4*>(&W[(j0 + jj) * IN_DIM + k0 + 4 * kq]);
            *reinterpret_cast<float4*>(&Ls[jj][4 * kq]) = v;
        }
        __syncthreads();
#pragma unroll
        for (int r = 0; r < 2; ++r) {
            const int idx = tid + r * 256;
            const int k8l = idx >> 6;       // 0..7
            const int jl  = idx & 63;
            const float4 a = *reinterpret_cast<const float4*>(&Ls[jl][8 * k8l]);
            const float4 b = *reinterpret_cast<const float4*>(&Ls[jl][8 * k8l + 4]);
            uint4 o;
            o.x = pk2(a.x, a.y); o.y = pk2(a.z, a.w);
            o.z = pk2(b.x, b.y); o.w = pk2(b.z, b.w);
            WT8[(size_t)(k0 / 8 + k8l) * OUT_DIM + j0 + jl] = o;
        }
    } else {
        // ---- X convert: blocks 64..319, 512 float4 each, fully coalesced ----
        const int cb = bid - 64;
        const float4* __restrict__ src = reinterpret_cast<const float4*>(X) + (size_t)cb * 512 + tid;
        uint2* __restrict__ dst = reinterpret_cast<uint2*>(Xh) + (size_t)cb * 512 + tid;
#pragma unroll
        for (int r = 0; r < 2; ++r) {
            const float4 v = src[r * 256];
            uint2 o;
            o.x = pk2(v.x, v.y);
            o.y = pk2(v.z, v.w);
            dst[r * 256] = o;
        }
    }
}

// ---------------- main ----------------
__global__ __launch_bounds__(1024, 2)
void MinPlus_70832600646269_kernel(const uint* __restrict__ Xh,
                                   const uint4* __restrict__ WT8,
                                   float* __restrict__ out)
{
    __shared__ uint  Xs[4][256];         // 4 KB: rows b0..b0+3 (256 uints = 512 halfs)
    __shared__ uint4 part[16][4][64];    // 64 KB: packed fp16-pair partials

    const int tid  = threadIdx.x;
    const int lane = tid & 63;
    const int wid  = tid >> 6;           // 0..15: k-chunk [32wid, 32wid+32)
    const int j0   = blockIdx.x * 256;
    const int b0   = blockIdx.y * 4;

    // ---- stage X tile: 256 uint4 (4 KB), threads 0..255, coalesced ----
    if (tid < 256)
        reinterpret_cast<uint4*>(&Xs[0][0])[tid] =
            reinterpret_cast<const uint4*>(Xh + (size_t)b0 * 256)[tid];

    uint acc2[4][4];                     // packed (k-even, k-odd) partial mins
#pragma unroll
    for (int b = 0; b < 4; ++b)
#pragma unroll
        for (int jq = 0; jq < 4; ++jq) acc2[b][jq] = 0x7C007C00u;  // +inf pair

    const uint4* __restrict__ wbase = WT8 + j0 + lane;
    const int g0 = wid * 4;              // first k8-group of this wave's chunk

    __syncthreads();                     // Xs ready

    // ---- 4 k8-quarters; W loaded per qt (lean live set; TLP hides latency) ----
#pragma unroll 1
    for (int qt = 0; qt < 4; ++qt) {
        uint4 w0 = wbase[(size_t)(g0 + qt) * OUT_DIM];
        uint4 w1 = wbase[(size_t)(g0 + qt) * OUT_DIM + 64];
        uint4 w2 = wbase[(size_t)(g0 + qt) * OUT_DIM + 128];
        uint4 w3 = wbase[(size_t)(g0 + qt) * OUT_DIM + 192];

#pragma unroll
        for (int b = 0; b < 4; ++b) {
            const uint4 x = *reinterpret_cast<const uint4*>(&Xs[b][wid * 16 + qt * 4]);

            acc2[b][0] = pk_min_h(acc2[b][0], pk_add_h(w0.x, x.x));
            acc2[b][0] = pk_min_h(acc2[b][0], pk_add_h(w0.y, x.y));
            acc2[b][0] = pk_min_h(acc2[b][0], pk_add_h(w0.z, x.z));
            acc2[b][0] = pk_min_h(acc2[b][0], pk_add_h(w0.w, x.w));

            acc2[b][1] = pk_min_h(acc2[b][1], pk_add_h(w1.x, x.x));
            acc2[b][1] = pk_min_h(acc2[b][1], pk_add_h(w1.y, x.y));
            acc2[b][1] = pk_min_h(acc2[b][1], pk_add_h(w1.z, x.z));
            acc2[b][1] = pk_min_h(acc2[b][1], pk_add_h(w1.w, x.w));

            acc2[b][2] = pk_min_h(acc2[b][2], pk_add_h(w2.x, x.x));
            acc2[b][2] = pk_min_h(acc2[b][2], pk_add_h(w2.y, x.y));
            acc2[b][2] = pk_min_h(acc2[b][2], pk_add_h(w2.z, x.z));
            acc2[b][2] = pk_min_h(acc2[b][2], pk_add_h(w2.w, x.w));

            acc2[b][3] = pk_min_h(acc2[b][3], pk_add_h(w3.x, x.x));
            acc2[b][3] = pk_min_h(acc2[b][3], pk_add_h(w3.y, x.y));
            acc2[b][3] = pk_min_h(acc2[b][3], pk_add_h(w3.z, x.z));
            acc2[b][3] = pk_min_h(acc2[b][3], pk_add_h(w3.w, x.w));
        }
    }

    // ---- per-wave packed partials: one ds_write_b128 per b ----
#pragma unroll
    for (int b = 0; b < 4; ++b)
        part[wid][b][lane] = make_uint4(acc2[b][0], acc2[b][1], acc2[b][2], acc2[b][3]);

    __syncthreads();

    // ---- combine 16 k-chunks: 1024 threads, one output each ----
    {
        const int b  = tid >> 8;         // 0..3
        const int jj = tid & 255;        // 0..255
        const int l  = jj & 63;
        const int c  = jj >> 6;          // which uint of the uint4

        uint m = reinterpret_cast<const uint*>(&part[0][b][l])[c];
#pragma unroll
        for (int p = 1; p < 16; ++p)
            m = pk_min_h(m, reinterpret_cast<const uint*>(&part[p][b][l])[c]);

        out[(size_t)(b0 + b) * OUT_DIM + j0 + jj] = fminf(h_lo(m), h_hi(m));
    }
}

extern "C" void kernel_launch(void* const* d_in, const int* in_sizes, int n_in,
                              void* d_out, int out_size, void* d_ws, size_t ws_size,
                              hipStream_t stream) {
    const float* X = (const float*)d_in[0];
    const float* W = (const float*)d_in[1];
    float* out = (float*)d_out;

    uint4* WT8 = (uint4*)d_ws;                              // 512 KB
    uint*  Xh  = (uint*)((char*)d_ws + (512 << 10));        // 1 MB

    MinPlus_pack_h<<<dim3(64 + 256), 256, 0, stream>>>(X, W, Xh, WT8);

    MinPlus_70832600646269_kernel<<<dim3(OUT_DIM / 256, B_DIM / 4), 1024, 0, stream>>>(Xh, WT8, out);
}